// Round 2
// 380.115 us; speedup vs baseline: 1.0164x; 1.0164x over previous
//
#include <hip/hip_runtime.h>

// Reference constants
#define L_LEN   8192
#define SEG     512
#define NFEATS  256
#define SCALE_2PI 6.283185307179586f
#define EPS_REF 1e-6f

// log2(10000)/128 : inv_dim_t for pair k = exp2(-k * STEP)
#define STEP_LOG2 0.1038102529652301f

// native vector type for nontemporal builtin (HIP float4 class is rejected)
typedef float floatx4 __attribute__((ext_vector_type(4)));

// ---------------- Phase 1: per-row segmented cumsum -> normalized x_embed ----
// One block per batch row. 1024 threads, each owns a contiguous chunk of 8.
// Scan: shfl-based intra-wave inclusive scan + 16 wave sums (4 barriers total,
// no 32KB LDS cumsum array — per-element cumsum stays in registers).
// Normalization: per-segment (cprev, SCALE/(clast-cprev+eps)) precomputed once
// into a 16-entry table; per element it's one subtract + one multiply.
__global__ __launch_bounds__(1024) void pe_phase1(const int* __restrict__ mask,
                                                  float* __restrict__ xe) {
    constexpr int THREADS = 1024;
    constexpr int CHUNK = L_LEN / THREADS; // 8

    __shared__ int waveSum[16];
    __shared__ int firstIdx;
    __shared__ int cAt[17];      // c at boundary indices start-1 + k*SEG
    __shared__ int cEnd;         // c[L-1]
    __shared__ float segCprev[16];
    __shared__ float segInv[16];

    const int t = threadIdx.x;
    const int lane = t & 63;
    const int wid = t >> 6;      // 16 waves
    const int b = blockIdx.x;
    const int base = t * CHUNK;
    const int* mrow = mask + (long)b * L_LEN;

    if (t == 0) firstIdx = L_LEN;

    // Load this thread's chunk (two int4)
    int m[CHUNK];
    const int4* mv = (const int4*)(mrow + base);
    int4 v0 = mv[0];
    int4 v1 = mv[1];
    m[0] = v0.x; m[1] = v0.y; m[2] = v0.z; m[3] = v0.w;
    m[4] = v1.x; m[5] = v1.y; m[6] = v1.z; m[7] = v1.w;

    // chunk sum + local first-valid
    int s = 0, lf = L_LEN;
#pragma unroll
    for (int j = 0; j < CHUNK; ++j) {
        if (m[j] != 0 && lf == L_LEN) lf = base + j;
        s += m[j];
    }
    __syncthreads();                       // B1: firstIdx init visible

    if (lf < L_LEN) atomicMin(&firstIdx, lf);

    // intra-wave inclusive scan of chunk sums (no barriers)
    int inc = s;
#pragma unroll
    for (int off = 1; off < 64; off <<= 1) {
        int vv = __shfl_up(inc, off);
        if (lane >= off) inc += vv;
    }
    if (lane == 63) waveSum[wid] = inc;
    __syncthreads();                       // B2: waveSum + firstIdx final

    int wavePrefix = 0;
    for (int w = 0; w < wid; ++w) wavePrefix += waveSum[w];
    const int start = firstIdx;
    const bool hv = (start < L_LEN);

    // per-element inclusive cumsum, in registers
    int run = wavePrefix + inc - s;        // exclusive prefix of this chunk
    int c[CHUNK];
#pragma unroll
    for (int j = 0; j < CHUNK; ++j) { run += m[j]; c[j] = run; }

    // record c at the segment-boundary indices {start-1 + k*SEG} and at L-1
#pragma unroll
    for (int j = 0; j < CHUNK; ++j) {
        const int i = base + j;
        const int d = i - start + 1;       // d==k*SEG  <=>  i == start-1+k*SEG
        if (d >= 0 && (d & (SEG - 1)) == 0) {
            const int q = d >> 9;          // d / SEG
            if (q <= 16) cAt[q] = c[j];
        }
        if (i == L_LEN - 1) cEnd = c[j];
    }
    __syncthreads();                       // B3: boundary table complete

    // build per-segment normalization table (<=16 live segments)
    if (hv && t < 16) {
        const int seg_start = start + t * SEG;
        if (seg_start < L_LEN) {
            const int cprev = (seg_start == 0) ? 0 : cAt[t];
            const int seg_end = min(seg_start + SEG, L_LEN);
            const int clast = (seg_end == L_LEN) ? cEnd : cAt[t + 1];
            segCprev[t] = (float)cprev;
            segInv[t] = SCALE_2PI / ((float)(clast - cprev) + EPS_REF);
        }
    }
    __syncthreads();                       // B4: segment table ready

    float e[CHUNK];
#pragma unroll
    for (int j = 0; j < CHUNK; ++j) {
        const int i = base + j;
        const int rel = i - start;
        float ev = 0.0f;
        if (hv && rel >= 0) {
            const int k = rel >> 9;        // rel / SEG, k in [0,15]
            ev = ((float)c[j] - segCprev[k]) * segInv[k];
        }
        e[j] = ev;
    }
    float4* xrow4 = (float4*)(xe + (long)b * L_LEN + base);
    xrow4[0] = make_float4(e[0], e[1], e[2], e[3]);
    xrow4[1] = make_float4(e[4], e[5], e[6], e[7]);
}

// ---------------- Phase 2: expand to sin/cos features (HBM-write bound) -----
// One wave per position per iteration; lane l covers feature pairs 2l, 2l+1
// -> one float4 store per lane = 1 KB coalesced per wave store.
// Block = 256 threads (4 waves), each block covers 16 positions.
// xe read as one wave-uniform float4 per wave (4 positions at once);
// output stored nontemporal (pure streaming, no reuse).
__global__ __launch_bounds__(256) void pe_phase2(const float4* __restrict__ xe4,
                                                 floatx4* __restrict__ out) {
    const int lane = threadIdx.x & 63;
    const int wave = threadIdx.x >> 6;

    // dim_t reciprocal, hoisted out of the position loop
    const float inv0 = exp2f(-(float)(2 * lane) * STEP_LOG2);
    const float inv1 = exp2f(-(float)(2 * lane + 1) * STEP_LOG2);

    const float4 ev = xe4[blockIdx.x * 4 + wave];  // 4 positions' x_embed
    const float ea[4] = {ev.x, ev.y, ev.z, ev.w};

    const int p0 = blockIdx.x * 16 + wave * 4;
#pragma unroll
    for (int j = 0; j < 4; ++j) {
        const float e = ea[j];
        float s0, c0, s1, c1;
        __sincosf(e * inv0, &s0, &c0);
        __sincosf(e * inv1, &s1, &c1);
        floatx4 v = {s0, c0, s1, c1};
        __builtin_nontemporal_store(v, &out[(long)(p0 + j) * (NFEATS / 4) + lane]);
    }
}

extern "C" void kernel_launch(void* const* d_in, const int* in_sizes, int n_in,
                              void* d_out, int out_size, void* d_ws, size_t ws_size,
                              hipStream_t stream) {
    // inputs: d_in[0] = x (unused), d_in[1] = mask (int32, B*L)
    const int* mask = (const int*)d_in[1];
    float* xe = (float*)d_ws;            // B*L floats = 1 MB scratch

    const int B = in_sizes[1] / L_LEN;   // 32
    const int npos = B * L_LEN;          // 262144

    pe_phase1<<<dim3(B), dim3(1024), 0, stream>>>(mask, xe);
    pe_phase2<<<dim3(npos / 16), dim3(256), 0, stream>>>((const float4*)xe,
                                                         (floatx4*)d_out);
}